// Round 3
// baseline (249.671 us; speedup 1.0000x reference)
//
#include <hip/hip_runtime.h>
#include <hip/hip_bf16.h>

#define NN 4096

typedef __attribute__((ext_vector_type(8))) short short8;
typedef __attribute__((ext_vector_type(4))) float f32x4;

// fp32 -> bf16 round-to-nearest-even
static __device__ __forceinline__ unsigned short f2bf(float x) {
    unsigned int u = __float_as_uint(x);
    u += 0x7fffu + ((u >> 16) & 1u);
    return (unsigned short)(u >> 16);
}

// async global->LDS, 16 bytes per lane (dest = wave-uniform base + lane*16)
static __device__ __forceinline__ void load_lds16(const unsigned short* g, unsigned short* l) {
    __builtin_amdgcn_global_load_lds(
        (const __attribute__((address_space(1))) unsigned int*)g,
        (__attribute__((address_space(3))) unsigned int*)l,
        16, 0, 0);
}

// ---- pre-pass 1: A -> bf16 masked tril (k <= i); extra blocks zero C tiles ----
// blocks [0,16384): convert A. blocks [16384, 16384+796): zero strict-upper tiles
// of C (496) + multi-chunk lower tiles that will receive atomicAdd partials (300).
__global__ __launch_bounds__(256) void convA_zero(const float* __restrict__ A,
                                                  unsigned short* __restrict__ Abf,
                                                  float* __restrict__ C) {
    if (blockIdx.x >= 16384) {
        const int t = blockIdx.x - 16384;
        const int tid = threadIdx.x;
        int bi, bj;
        if (t < 496) {
            int u = t;
            int e = (int)((sqrtf(8.f * (float)u + 1.f) - 1.f) * 0.5f);
            while ((e + 1) * (e + 2) / 2 <= u) ++e;
            while (e * (e + 1) / 2 > u) --e;
            int r = u - e * (e + 1) / 2;
            bi = r; bj = e + 1;                     // strict upper
        } else {
            int u = t - 496;
            int d = 8;
            for (; d < 32; ++d) { int cnt = 32 - d; if (u < cnt) break; u -= cnt; }
            bj = u; bi = u + d;                     // lower, d >= 8 (atomic targets)
        }
        const float4 z = make_float4(0.f, 0.f, 0.f, 0.f);
        #pragma unroll
        for (int it = 0; it < 16; ++it) {
            int idx = it * 256 + tid;
            int rr = idx >> 5;
            int c4 = (idx & 31) << 2;
            *(float4*)&C[(size_t)(bi * 128 + rr) * NN + bj * 128 + c4] = z;
        }
        return;
    }
    int t = blockIdx.x * 256 + threadIdx.x;         // float4 index
    int row = t >> 10;
    int c4 = (t & 1023) << 2;
    const float4 v = *(const float4*)(A + ((size_t)row << 12) + c4);
    ushort4 o;
    o.x = (c4 + 0 <= row) ? f2bf(v.x) : (unsigned short)0;
    o.y = (c4 + 1 <= row) ? f2bf(v.y) : (unsigned short)0;
    o.z = (c4 + 2 <= row) ? f2bf(v.z) : (unsigned short)0;
    o.w = (c4 + 3 <= row) ? f2bf(v.w) : (unsigned short)0;
    *(ushort4*)(Abf + ((size_t)row << 12) + c4) = o;
}

// ---- pre-pass 2: B -> bf16 masked tril (k >= j), transposed: Bt[n][k] ----
__global__ __launch_bounds__(256) void convB(const float* __restrict__ B,
                                             unsigned short* __restrict__ Bt) {
    __shared__ float tile[64][65];
    const int n0 = blockIdx.x * 64;
    const int k0 = blockIdx.y * 64;
    const int t = threadIdx.x;
    #pragma unroll
    for (int p = 0; p < 4; ++p) {
        int idx = p * 256 + t;
        int kr  = idx >> 4;
        int c4  = (idx & 15) << 2;
        const float4 v = *(const float4*)(B + (size_t)(k0 + kr) * NN + n0 + c4);
        tile[kr][c4 + 0] = v.x; tile[kr][c4 + 1] = v.y;
        tile[kr][c4 + 2] = v.z; tile[kr][c4 + 3] = v.w;
    }
    __syncthreads();
    #pragma unroll
    for (int p = 0; p < 4; ++p) {
        int idx = p * 256 + t;
        int nr  = idx >> 4;
        int k4  = (idx & 15) << 2;
        int gn  = n0 + nr;
        ushort4 o;
        o.x = (k0 + k4 + 0 >= gn) ? f2bf(tile[k4 + 0][nr]) : (unsigned short)0;
        o.y = (k0 + k4 + 1 >= gn) ? f2bf(tile[k4 + 1][nr]) : (unsigned short)0;
        o.z = (k0 + k4 + 2 >= gn) ? f2bf(tile[k4 + 2][nr]) : (unsigned short)0;
        o.w = (k0 + k4 + 3 >= gn) ? f2bf(tile[k4 + 3][nr]) : (unsigned short)0;
        *(ushort4*)(Bt + (size_t)gn * NN + k0 + k4) = o;
    }
}

// ---- main GEMM: 128x128 tile, BK=32, split-K (<=32 steps/unit), LDS double-buffer ----
// 1000 units, decoded longest-first (d=31 at blockIdx 0). One barrier per K-step:
// barrier -> prefetch next tile (async) -> compute current. The barrier's vmcnt(0)
// drain waits only on the prefetch remainder (it overlapped the previous compute).
__global__ __launch_bounds__(256, 4) void gemm_tril_sk(const unsigned short* __restrict__ Abf,
                                                       const unsigned short* __restrict__ Btb,
                                                       float* __restrict__ C) {
    const int tid = threadIdx.x;

    // decode unit id -> (bi, bj, chunk c, chunks-per-tile m); d descends (longest first)
    int u = blockIdx.x, d, m = 1;
    for (d = 31; d > 0; --d) {
        m = (d + 8) >> 3;                           // ceil((d+1)/8)
        int cnt = (32 - d) * m;
        if (u < cnt) break;
        u -= cnt;
    }
    if (d == 0) m = 1;
    const int blk = u / m;
    const int c   = u - blk * m;
    const int bj = blk, bi = blk + d;

    __shared__ __attribute__((aligned(16))) unsigned short sh[2][2][128 * 32];

    const int lane = tid & 63;
    const int w    = tid >> 6;
    const int wm   = w >> 1, wn = w & 1;
    const int l15  = lane & 15, quad = lane >> 4;

    // per-thread staging offsets (two 16B chunks per matrix per step)
    const size_t offA0 = (size_t)(bi * 128 + (tid >> 2)) * NN + (tid & 3) * 8;
    const size_t offA1 = offA0 + (size_t)64 * NN;
    const size_t offB0 = (size_t)(bj * 128 + (tid >> 2)) * NN + (tid & 3) * 8;
    const size_t offB1 = offB0 + (size_t)64 * NN;
    unsigned short* ldsA0 = &sh[0][0][tid * 8];
    unsigned short* ldsA1 = &sh[0][0][(256 + tid) * 8];
    unsigned short* ldsB0 = &sh[0][1][tid * 8];
    unsigned short* ldsB1 = &sh[0][1][(256 + tid) * 8];
    const int bufStride = 2 * 128 * 32;             // elements between sh[0] and sh[1]

    f32x4 acc[4][4];
    const f32x4 zero4 = {0.f, 0.f, 0.f, 0.f};
    #pragma unroll
    for (int i = 0; i < 4; ++i)
        #pragma unroll
        for (int j = 0; j < 4; ++j) acc[i][j] = zero4;

    const int kbB = (bj << 2) + c * 32;
    const int kbE = min(kbB + 32, (bi << 2) + 4);   // exclusive
    const int nst = kbE - kbB;

    // prologue: stage step 0 into buffer 0
    {
        const int koff = kbB << 5;
        load_lds16(Abf + offA0 + koff, ldsA0);
        load_lds16(Abf + offA1 + koff, ldsA1);
        load_lds16(Btb + offB0 + koff, ldsB0);
        load_lds16(Btb + offB1 + koff, ldsB1);
    }

    for (int s = 0; s < nst; ++s) {
        const int cur = s & 1;
        __syncthreads();                            // drains prefetch for step s
        if (s + 1 < nst) {
            const int koff = (kbB + s + 1) << 5;
            const int bo = (cur ^ 1) * bufStride;
            load_lds16(Abf + offA0 + koff, ldsA0 + bo);
            load_lds16(Abf + offA1 + koff, ldsA1 + bo);
            load_lds16(Btb + offB0 + koff, ldsB0 + bo);
            load_lds16(Btb + offB1 + koff, ldsB1 + bo);
        }
        const unsigned short* As = sh[cur][0];
        const unsigned short* Bs = sh[cur][1];
        short8 a[4], b[4];
        #pragma unroll
        for (int mt = 0; mt < 4; ++mt)
            a[mt] = *(const short8*)&As[(wm * 64 + mt * 16 + l15) * 32 + quad * 8];
        #pragma unroll
        for (int nt = 0; nt < 4; ++nt)
            b[nt] = *(const short8*)&Bs[(wn * 64 + nt * 16 + l15) * 32 + quad * 8];
        #pragma unroll
        for (int mt = 0; mt < 4; ++mt)
            #pragma unroll
            for (int nt = 0; nt < 4; ++nt)
                acc[mt][nt] = __builtin_amdgcn_mfma_f32_16x16x32_bf16(a[mt], b[nt], acc[mt][nt], 0, 0, 0);
    }

    // epilogue: C/D layout col=lane&15, row=quad*4+reg (m89-verified)
    if (m == 1) {
        #pragma unroll
        for (int mt = 0; mt < 4; ++mt) {
            #pragma unroll
            for (int nt = 0; nt < 4; ++nt) {
                const int gj  = bj * 128 + wn * 64 + nt * 16 + l15;
                const int gi0 = bi * 128 + wm * 64 + mt * 16 + quad * 4;
                #pragma unroll
                for (int rr = 0; rr < 4; ++rr) {
                    int gi = gi0 + rr;
                    float v = acc[mt][nt][rr];
                    C[(size_t)gi * NN + gj] = (d > 0 || gi >= gj) ? v : 0.f;
                }
            }
        }
    } else {
        #pragma unroll
        for (int mt = 0; mt < 4; ++mt) {
            #pragma unroll
            for (int nt = 0; nt < 4; ++nt) {
                const int gj  = bj * 128 + wn * 64 + nt * 16 + l15;
                const int gi0 = bi * 128 + wm * 64 + mt * 16 + quad * 4;
                #pragma unroll
                for (int rr = 0; rr < 4; ++rr) {
                    int gi = gi0 + rr;
                    atomicAdd(&C[(size_t)gi * NN + gj], acc[mt][nt][rr]);
                }
            }
        }
    }
}

// ---- fallback (ws too small): fp32 LDS-tiled, correct-but-slow ----
__global__ void gemm_fallback(const float* __restrict__ A, const float* __restrict__ B,
                              float* __restrict__ C) {
    const int bi = blockIdx.y, bj = blockIdx.x;
    const int ty = threadIdx.y, tx = threadIdx.x;
    const int gi = bi * 32 + ty, gj = bj * 32 + tx;
    if (bi < bj) { C[(size_t)gi * NN + gj] = 0.f; return; }
    __shared__ float As[32][33], Bs[32][33];
    float s = 0.f;
    for (int kt = bj; kt <= bi; ++kt) {
        const int k = kt * 32;
        float av = A[(size_t)gi * NN + k + tx];
        As[ty][tx] = (k + tx <= gi) ? av : 0.f;
        float bv = B[(size_t)(k + ty) * NN + gj];
        Bs[ty][tx] = (k + ty >= gj) ? bv : 0.f;
        __syncthreads();
        #pragma unroll
        for (int kk = 0; kk < 32; ++kk) s += As[ty][kk] * Bs[kk][tx];
        __syncthreads();
    }
    C[(size_t)gi * NN + gj] = (gi >= gj) ? s : 0.f;
}

extern "C" void kernel_launch(void* const* d_in, const int* in_sizes, int n_in,
                              void* d_out, int out_size, void* d_ws, size_t ws_size,
                              hipStream_t stream) {
    const float* A = (const float*)d_in[0];
    const float* B = (const float*)d_in[1];
    float* C = (float*)d_out;

    const size_t need = (size_t)2 * NN * NN * sizeof(unsigned short);  // 64 MB
    if (ws_size >= need) {
        unsigned short* Abf = (unsigned short*)d_ws;
        unsigned short* Btb = Abf + (size_t)NN * NN;
        convA_zero<<<dim3(16384 + 796), dim3(256), 0, stream>>>(A, Abf, C);
        convB<<<dim3(64, 64), dim3(256), 0, stream>>>(B, Btb);
        gemm_tril_sk<<<dim3(1000), dim3(256), 0, stream>>>(Abf, Btb, C);
    } else {
        gemm_fallback<<<dim3(128, 128), dim3(32, 32), 0, stream>>>(A, B, C);
    }
}